// Round 1
// baseline (292.446 us; speedup 1.0000x reference)
//
#include <hip/hip_runtime.h>

#define N_NODES 16384
#define N_EDGES 524288
// D_IN=3, D_HID=16, D_OUT=16

// ---------------- kernel 1: zero the aggregation buffer ----------------
__global__ void zero_agg_kernel(float* __restrict__ agg) {
    int i = blockIdx.x * blockDim.x + threadIdx.x;
    if (i < N_NODES * 3) agg[i] = 0.0f;
}

// ---------------- kernel 2: scatter-add neighbor features ----------------
__global__ void scatter_kernel(const int* __restrict__ eidx,
                               const float* __restrict__ x,
                               float* __restrict__ agg) {
    int e = blockIdx.x * blockDim.x + threadIdx.x;
    if (e >= N_EDGES) return;
    int s = eidx[e];            // src row
    int t = eidx[N_EDGES + e];  // tgt row
    float f0 = x[s * 3 + 0];
    float f1 = x[s * 3 + 1];
    float f2 = x[s * 3 + 2];
    atomicAdd(&agg[t * 3 + 0], f0);
    atomicAdd(&agg[t * 3 + 1], f1);
    atomicAdd(&agg[t * 3 + 2], f2);
}

// ---------------- kernel 3: GIN MLP per node -> h [N,16] ----------------
__global__ void mlp_kernel(const float* __restrict__ x,
                           const float* __restrict__ agg,
                           const float* __restrict__ W1,
                           const float* __restrict__ b1,
                           const float* __restrict__ W2,
                           const float* __restrict__ b2,
                           const float* __restrict__ eps_p,
                           float* __restrict__ h) {
    int n = blockIdx.x * blockDim.x + threadIdx.x;
    if (n >= N_NODES) return;
    float se = 1.0f + eps_p[0];
    float z0 = se * x[n * 3 + 0] + agg[n * 3 + 0];
    float z1 = se * x[n * 3 + 1] + agg[n * 3 + 1];
    float z2 = se * x[n * 3 + 2] + agg[n * 3 + 2];
    float h1[16];
#pragma unroll
    for (int j = 0; j < 16; ++j) {
        float a = b1[j];
        a += z0 * W1[0 * 16 + j];
        a += z1 * W1[1 * 16 + j];
        a += z2 * W1[2 * 16 + j];
        h1[j] = fmaxf(a, 0.0f);
    }
    float4* h4 = (float4*)&h[n * 16];
#pragma unroll
    for (int oq = 0; oq < 4; ++oq) {
        float4 o;
        float* op = (float*)&o;
#pragma unroll
        for (int c = 0; c < 4; ++c) {
            int oo = oq * 4 + c;
            float a = b2[oo];
#pragma unroll
            for (int j = 0; j < 16; ++j) a += h1[j] * W2[j * 16 + oo];
            op[c] = fmaxf(a, 0.0f);
        }
        h4[oq] = o;
    }
}

// ---------------- kernel 4: out[i][j] = dot(h[i], h[j]) ----------------
// 128x128 tile per 256-thread block. hjT transposed in LDS so the per-thread
// register load of 4 consecutive j columns is a stride-1 ds_read_b128.
__global__ __launch_bounds__(256) void pairwise_kernel(const float* __restrict__ h,
                                                       float* __restrict__ out) {
    __shared__ float hi[128 * 16];    // 8 KB, row-major
    __shared__ float hjT[16][128];    // 8 KB, transposed
    const int i0 = blockIdx.y * 128;
    const int j0 = blockIdx.x * 128;
    const int tid = threadIdx.x;

    const float4* h4 = (const float4*)h;
    float4* hi4 = (float4*)hi;
#pragma unroll
    for (int k = 0; k < 2; ++k) {
        int idx = tid + k * 256;  // 0..511 (128 rows x 4 float4)
        float4 v = h4[(size_t)i0 * 4 + idx];
        hi4[idx] = v;
        float4 w = h4[(size_t)j0 * 4 + idx];
        int row = idx >> 2, q = idx & 3;
        hjT[q * 4 + 0][row] = w.x;
        hjT[q * 4 + 1][row] = w.y;
        hjT[q * 4 + 2][row] = w.z;
        hjT[q * 4 + 3][row] = w.w;
    }
    __syncthreads();

    const int tx = tid & 31;  // j-group: 4 consecutive j per thread
    const int ty = tid >> 5;  // 0..7 -> 16 i-rows per thread

    // 4 j-columns of the j-tile, 16 k-slices, in registers (64 VGPR)
    float4 hj[16];
#pragma unroll
    for (int k = 0; k < 16; ++k) hj[k] = *(const float4*)&hjT[k][tx * 4];

    float4* out4 = (float4*)out;
    const size_t obase = (size_t)(i0 + ty * 16) * (N_NODES / 4) + (size_t)(j0 >> 2) + tx;

#pragma unroll
    for (int r = 0; r < 16; ++r) {
        const float4* hir4 = (const float4*)&hi[(ty * 16 + r) * 16];
        float4 A0 = hir4[0], A1 = hir4[1], A2 = hir4[2], A3 = hir4[3];
        float4 acc = make_float4(0.f, 0.f, 0.f, 0.f);
        const float* ap = (const float*)&A0;
#pragma unroll
        for (int k = 0; k < 4; ++k) {
            float a = ap[k];
            acc.x += a * hj[k].x; acc.y += a * hj[k].y;
            acc.z += a * hj[k].z; acc.w += a * hj[k].w;
        }
        ap = (const float*)&A1;
#pragma unroll
        for (int k = 0; k < 4; ++k) {
            float a = ap[k];
            acc.x += a * hj[4 + k].x; acc.y += a * hj[4 + k].y;
            acc.z += a * hj[4 + k].z; acc.w += a * hj[4 + k].w;
        }
        ap = (const float*)&A2;
#pragma unroll
        for (int k = 0; k < 4; ++k) {
            float a = ap[k];
            acc.x += a * hj[8 + k].x; acc.y += a * hj[8 + k].y;
            acc.z += a * hj[8 + k].z; acc.w += a * hj[8 + k].w;
        }
        ap = (const float*)&A3;
#pragma unroll
        for (int k = 0; k < 4; ++k) {
            float a = ap[k];
            acc.x += a * hj[12 + k].x; acc.y += a * hj[12 + k].y;
            acc.z += a * hj[12 + k].z; acc.w += a * hj[12 + k].w;
        }
        out4[obase + (size_t)r * (N_NODES / 4)] = acc;
    }
}

extern "C" void kernel_launch(void* const* d_in, const int* in_sizes, int n_in,
                              void* d_out, int out_size, void* d_ws, size_t ws_size,
                              hipStream_t stream) {
    const float* node_feats = (const float*)d_in[0];
    const int*   edge_idx   = (const int*)d_in[1];
    const float* W1         = (const float*)d_in[2];
    const float* b1         = (const float*)d_in[3];
    const float* W2         = (const float*)d_in[4];
    const float* b2         = (const float*)d_in[5];
    const float* eps        = (const float*)d_in[6];
    float* out = (float*)d_out;

    // workspace layout: agg [N*3 floats] at 0, h [N*16 floats] at 256 KB
    float* agg = (float*)d_ws;
    float* h   = (float*)((char*)d_ws + 262144);

    zero_agg_kernel<<<(N_NODES * 3 + 255) / 256, 256, 0, stream>>>(agg);
    scatter_kernel<<<N_EDGES / 256, 256, 0, stream>>>(edge_idx, node_feats, agg);
    mlp_kernel<<<N_NODES / 256, 256, 0, stream>>>(node_feats, agg, W1, b1, W2, b2, eps, h);

    dim3 grid(N_NODES / 128, N_NODES / 128);
    pairwise_kernel<<<grid, 256, 0, stream>>>(h, out);
}

// Round 3
// 271.458 us; speedup vs baseline: 1.0773x; 1.0773x over previous
//
#include <hip/hip_runtime.h>

#define N_NODES 16384
#define N_EDGES 524288
#define TILE_I 128
#define TILE_J 256
// D_IN=3, D_HID=16, D_OUT=16

typedef float f32x4 __attribute__((ext_vector_type(4)));

// ---------------- kernel 1: zero the aggregation buffer ----------------
__global__ void zero_agg_kernel(float* __restrict__ agg) {
    int i = blockIdx.x * blockDim.x + threadIdx.x;
    if (i < N_NODES * 3) agg[i] = 0.0f;
}

// ---------------- kernel 2: scatter-add neighbor features ----------------
__global__ void scatter_kernel(const int* __restrict__ eidx,
                               const float* __restrict__ x,
                               float* __restrict__ agg) {
    int e = blockIdx.x * blockDim.x + threadIdx.x;
    if (e >= N_EDGES) return;
    int s = eidx[e];            // src row
    int t = eidx[N_EDGES + e];  // tgt row
    float f0 = x[s * 3 + 0];
    float f1 = x[s * 3 + 1];
    float f2 = x[s * 3 + 2];
    atomicAdd(&agg[t * 3 + 0], f0);
    atomicAdd(&agg[t * 3 + 1], f1);
    atomicAdd(&agg[t * 3 + 2], f2);
}

// ---------------- kernel 3: GIN MLP per node -> h [N,16] ----------------
__global__ void mlp_kernel(const float* __restrict__ x,
                           const float* __restrict__ agg,
                           const float* __restrict__ W1,
                           const float* __restrict__ b1,
                           const float* __restrict__ W2,
                           const float* __restrict__ b2,
                           const float* __restrict__ eps_p,
                           float* __restrict__ h) {
    int n = blockIdx.x * blockDim.x + threadIdx.x;
    if (n >= N_NODES) return;
    float se = 1.0f + eps_p[0];
    float z0 = se * x[n * 3 + 0] + agg[n * 3 + 0];
    float z1 = se * x[n * 3 + 1] + agg[n * 3 + 1];
    float z2 = se * x[n * 3 + 2] + agg[n * 3 + 2];
    float h1[16];
#pragma unroll
    for (int j = 0; j < 16; ++j) {
        float a = b1[j];
        a += z0 * W1[0 * 16 + j];
        a += z1 * W1[1 * 16 + j];
        a += z2 * W1[2 * 16 + j];
        h1[j] = fmaxf(a, 0.0f);
    }
    float4* h4 = (float4*)&h[n * 16];
#pragma unroll
    for (int oq = 0; oq < 4; ++oq) {
        float4 o;
        float* op = (float*)&o;
#pragma unroll
        for (int c = 0; c < 4; ++c) {
            int oo = oq * 4 + c;
            float a = b2[oo];
#pragma unroll
            for (int j = 0; j < 16; ++j) a += h1[j] * W2[j * 16 + oo];
            op[c] = fmaxf(a, 0.0f);
        }
        h4[oq] = o;
    }
}

// ---------------- kernel 4: out[i][j] = dot(h[i], h[j]) ----------------
// 128x256 tile, 512 threads. tx = tid&63 -> each wave's store is one fully
// contiguous 1 KB segment; hi row reads are full-wave LDS broadcasts.
// Nontemporal stores keep the 1.07 GB output stream out of L2.
__global__ __launch_bounds__(512) void pairwise_kernel(const float* __restrict__ h,
                                                       float* __restrict__ out) {
    __shared__ float hi[TILE_I * 16];    // 8 KB, row-major
    __shared__ float hjT[16][TILE_J];    // 16 KB, transposed
    const int i0 = blockIdx.y * TILE_I;
    const int j0 = blockIdx.x * TILE_J;
    const int tid = threadIdx.x;

    const float4* h4 = (const float4*)h;
    float4* hi4 = (float4*)hi;
    // hi: 128 rows x 4 float4 = 512 float4, one per thread
    hi4[tid] = h4[(size_t)i0 * 4 + tid];
    // hjT: 256 rows -> transposed, 1024 float4 in two rounds
#pragma unroll
    for (int k = 0; k < 2; ++k) {
        int idx = tid + k * 512;
        float4 w = h4[(size_t)j0 * 4 + idx];
        int row = idx >> 2, q = idx & 3;
        hjT[q * 4 + 0][row] = w.x;
        hjT[q * 4 + 1][row] = w.y;
        hjT[q * 4 + 2][row] = w.z;
        hjT[q * 4 + 3][row] = w.w;
    }
    __syncthreads();

    const int tx = tid & 63;  // 4 consecutive j (float4) per lane; wave = 256 j
    const int ty = tid >> 6;  // 0..7 -> 16 i-rows per thread

    // 4 j-columns of the j-tile, 16 k-slices, in registers (64 VGPR)
    float4 hj[16];
#pragma unroll
    for (int k = 0; k < 16; ++k) hj[k] = *(const float4*)&hjT[k][tx * 4];

    f32x4* out4 = (f32x4*)out;
    const size_t obase = (size_t)(i0 + ty * 16) * (N_NODES / 4) + (size_t)(j0 >> 2) + tx;

#pragma unroll
    for (int r = 0; r < 16; ++r) {
        const float4* hir4 = (const float4*)&hi[(ty * 16 + r) * 16];
        float4 A0 = hir4[0], A1 = hir4[1], A2 = hir4[2], A3 = hir4[3];
        float4 acc = make_float4(0.f, 0.f, 0.f, 0.f);
        const float* ap = (const float*)&A0;
#pragma unroll
        for (int k = 0; k < 4; ++k) {
            float a = ap[k];
            acc.x += a * hj[k].x; acc.y += a * hj[k].y;
            acc.z += a * hj[k].z; acc.w += a * hj[k].w;
        }
        ap = (const float*)&A1;
#pragma unroll
        for (int k = 0; k < 4; ++k) {
            float a = ap[k];
            acc.x += a * hj[4 + k].x; acc.y += a * hj[4 + k].y;
            acc.z += a * hj[4 + k].z; acc.w += a * hj[4 + k].w;
        }
        ap = (const float*)&A2;
#pragma unroll
        for (int k = 0; k < 4; ++k) {
            float a = ap[k];
            acc.x += a * hj[8 + k].x; acc.y += a * hj[8 + k].y;
            acc.z += a * hj[8 + k].z; acc.w += a * hj[8 + k].w;
        }
        ap = (const float*)&A3;
#pragma unroll
        for (int k = 0; k < 4; ++k) {
            float a = ap[k];
            acc.x += a * hj[12 + k].x; acc.y += a * hj[12 + k].y;
            acc.z += a * hj[12 + k].z; acc.w += a * hj[12 + k].w;
        }
        f32x4 accv = { acc.x, acc.y, acc.z, acc.w };
        __builtin_nontemporal_store(accv, &out4[obase + (size_t)r * (N_NODES / 4)]);
    }
}

extern "C" void kernel_launch(void* const* d_in, const int* in_sizes, int n_in,
                              void* d_out, int out_size, void* d_ws, size_t ws_size,
                              hipStream_t stream) {
    const float* node_feats = (const float*)d_in[0];
    const int*   edge_idx   = (const int*)d_in[1];
    const float* W1         = (const float*)d_in[2];
    const float* b1         = (const float*)d_in[3];
    const float* W2         = (const float*)d_in[4];
    const float* b2         = (const float*)d_in[5];
    const float* eps        = (const float*)d_in[6];
    float* out = (float*)d_out;

    // workspace layout: agg [N*3 floats] at 0, h [N*16 floats] at 256 KB
    float* agg = (float*)d_ws;
    float* h   = (float*)((char*)d_ws + 262144);

    zero_agg_kernel<<<(N_NODES * 3 + 255) / 256, 256, 0, stream>>>(agg);
    scatter_kernel<<<N_EDGES / 256, 256, 0, stream>>>(edge_idx, node_feats, agg);
    mlp_kernel<<<N_NODES / 64, 64, 0, stream>>>(node_feats, agg, W1, b1, W2, b2, eps, h);

    dim3 grid(N_NODES / TILE_J, N_NODES / TILE_I);
    pairwise_kernel<<<grid, 512, 0, stream>>>(h, out);
}